// Round 5
// baseline (460.679 us; speedup 1.0000x reference)
//
#include <hip/hip_runtime.h>

#define Kst 256
#define Dd 256
#define Vv 50000
#define Tt 512
#define Bb 256
#define KP1 257
#define MD 512
#define NROWS (KP1*KP1)   // 66049
#define EPSf 1e-5f

#define VB2 196           // ceil(50000/256) vocab blocks for MFMA emission kernel

typedef __attribute__((ext_vector_type(8))) short short8;
typedef __attribute__((ext_vector_type(4))) short short4v;
typedef __attribute__((ext_vector_type(4))) float f32x4;
typedef __attribute__((ext_vector_type(4))) unsigned u32x4;

__device__ __forceinline__ unsigned short f2bf(float f) {
    unsigned u = __builtin_bit_cast(unsigned, f);
    unsigned r = (u + 0x7fffu + ((u >> 16) & 1u)) >> 16;
    return (unsigned short)r;
}
__device__ __forceinline__ float bf2f(unsigned short u) {
    return __builtin_bit_cast(float, ((unsigned)u) << 16);
}
__device__ __forceinline__ unsigned bfpack(float lo, float hi) {
    return __builtin_amdgcn_perm(__builtin_bit_cast(unsigned, hi),
                                 __builtin_bit_cast(unsigned, lo), 0x07060302u);
}

// ---------------- K1: emission hidden h = LN(lembs + relu(lembs@em_W.T + b)) -> bf16 ----------------
__global__ __launch_bounds__(256) void k_h(
    const float* __restrict__ lembs, const float* __restrict__ em_W,
    const float* __restrict__ em_bias, const float* __restrict__ em_g,
    const float* __restrict__ em_beta, unsigned short* __restrict__ h_bf)
{
    int k = blockIdx.x, d = threadIdx.x;
    __shared__ float lrow[Dd];
    __shared__ float red[256];
    lrow[d] = lembs[k*Dd + d];
    __syncthreads();
    float acc = em_bias[d];
    const float4* w4 = (const float4*)(em_W + (size_t)d*Dd);
    for (int j4 = 0; j4 < Dd/4; ++j4) {
        float4 w = w4[j4];
        acc += w.x*lrow[4*j4] + w.y*lrow[4*j4+1] + w.z*lrow[4*j4+2] + w.w*lrow[4*j4+3];
    }
    float val = lrow[d] + fmaxf(acc, 0.f);
    red[d] = val; __syncthreads();
    for (int s = 128; s > 0; s >>= 1) { if (d < s) red[d] += red[d+s]; __syncthreads(); }
    float mu = red[0] * (1.f/Dd);
    __syncthreads();
    float c = val - mu;
    red[d] = c*c; __syncthreads();
    for (int s = 128; s > 0; s >>= 1) { if (d < s) red[d] += red[d+s]; __syncthreads(); }
    float rstd = rsqrtf(red[0] * (1.f/Dd) + EPSf);
    float o = c * rstd * em_g[d] + em_beta[d];
    h_bf[k*Dd + d] = f2bf(o);
}

// ---------------- K2: P0[i,j] = tlembs[i]@tm_W[j,0:256], P1[i,j] = tlembs[i]@tm_W[j,256:512] ----------------
__global__ __launch_bounds__(256) void k_P(
    const float* __restrict__ tlembs, const float* __restrict__ tm_W,
    float* __restrict__ P0, float* __restrict__ P1)
{
    int i = blockIdx.x;            // 0..256
    int tid = threadIdx.x;
    __shared__ float tl[Dd];
    tl[tid] = tlembs[i*Dd + tid];
    __syncthreads();
    for (int half = 0; half < 2; ++half) {
        int j = tid + half*256;
        float a0 = 0.f, a1 = 0.f;
        const float4* w4 = (const float4*)(tm_W + (size_t)j*MD);
        for (int l4 = 0; l4 < 64; ++l4) {
            float4 w = w4[l4];
            a0 += w.x*tl[4*l4] + w.y*tl[4*l4+1] + w.z*tl[4*l4+2] + w.w*tl[4*l4+3];
        }
        for (int l4 = 64; l4 < 128; ++l4) {
            float4 w = w4[l4];
            int l = 4*l4 - 256;
            a1 += w.x*tl[l] + w.y*tl[l+1] + w.z*tl[l+2] + w.w*tl[l+3];
        }
        P0[(size_t)i*MD + j] = a0;
        P1[(size_t)i*MD + j] = a1;
    }
}

// ---------------- K2b: td_W -> bf16 copy ----------------
__global__ __launch_bounds__(256) void k_tdw(
    const float* __restrict__ td_W, unsigned short* __restrict__ tdw_bf)
{
    int i = blockIdx.x*256 + threadIdx.x;
    float4 v = ((const float4*)td_W)[i];
    short4v o;
    o.x = (short)f2bf(v.x); o.y = (short)f2bf(v.y);
    o.z = (short)f2bf(v.z); o.w = (short)f2bf(v.w);
    *(short4v*)(tdw_bf + (size_t)i*4) = o;
}

// ---------------- K3 (MFMA): emission logits E[v][k] (bf16) + logsumexp partials ----------------
__global__ __launch_bounds__(256) void k_em_mfma(
    const float* __restrict__ dec_W, const float* __restrict__ dec_b,
    const unsigned short* __restrict__ h_bf, float* __restrict__ part,
    unsigned short* __restrict__ E)
{
    int vb = blockIdx.x, kg = blockIdx.y;
    int tid = threadIdx.x, lane = tid & 63, wv = tid >> 6;
    int l15 = lane & 15, q = lane >> 4;
    __shared__ short hs[64][264];      // stride 264: 2-way bank aliasing (free)
    __shared__ float red[4][64];
    __shared__ float gmax[64];

    {
        int row = tid >> 2, c0 = (tid & 3) * 64;
        const short8* src = (const short8*)(h_bf + (size_t)(kg*64 + row)*Dd + c0);
        #pragma unroll
        for (int u = 0; u < 8; ++u)
            *(short8*)&hs[row][c0 + u*8] = src[u];
    }
    __syncthreads();

    const float* aptr[4];
    #pragma unroll
    for (int mt = 0; mt < 4; ++mt) {
        int v = vb*256 + wv*64 + mt*16 + l15;
        if (v > Vv-1) v = Vv-1;
        aptr[mt] = dec_W + (size_t)v*Dd + q*8;
    }
    f32x4 acc[4][4];
    #pragma unroll
    for (int mt = 0; mt < 4; ++mt)
        #pragma unroll
        for (int nt = 0; nt < 4; ++nt)
            acc[mt][nt] = (f32x4){0.f,0.f,0.f,0.f};

    for (int ks = 0; ks < 8; ++ks) {
        short8 a[4];
        #pragma unroll
        for (int mt = 0; mt < 4; ++mt) {
            float4 f0 = *(const float4*)(aptr[mt] + ks*32);
            float4 f1 = *(const float4*)(aptr[mt] + ks*32 + 4);
            u32x4 pk;
            pk.x = bfpack(f0.x, f0.y);
            pk.y = bfpack(f0.z, f0.w);
            pk.z = bfpack(f1.x, f1.y);
            pk.w = bfpack(f1.z, f1.w);
            a[mt] = __builtin_bit_cast(short8, pk);
        }
        short8 b0 = *(const short8*)&hs[ 0 + l15][ks*32 + q*8];
        short8 b1 = *(const short8*)&hs[16 + l15][ks*32 + q*8];
        short8 b2 = *(const short8*)&hs[32 + l15][ks*32 + q*8];
        short8 b3 = *(const short8*)&hs[48 + l15][ks*32 + q*8];
        #pragma unroll
        for (int mt = 0; mt < 4; ++mt) {
            acc[mt][0] = __builtin_amdgcn_mfma_f32_16x16x32_bf16(a[mt], b0, acc[mt][0], 0,0,0);
            acc[mt][1] = __builtin_amdgcn_mfma_f32_16x16x32_bf16(a[mt], b1, acc[mt][1], 0,0,0);
            acc[mt][2] = __builtin_amdgcn_mfma_f32_16x16x32_bf16(a[mt], b2, acc[mt][2], 0,0,0);
            acc[mt][3] = __builtin_amdgcn_mfma_f32_16x16x32_bf16(a[mt], b3, acc[mt][3], 0,0,0);
        }
    }

    // add dec_b, store bf16 logits, mask OOB rows (C layout: row=q*4+reg, col=nt*16+l15)
    #pragma unroll
    for (int mt = 0; mt < 4; ++mt) {
        int vbase = vb*256 + wv*64 + mt*16 + q*4;
        #pragma unroll
        for (int reg = 0; reg < 4; ++reg) {
            int v = vbase + reg;
            if (v < Vv) {
                float db = dec_b[v];
                #pragma unroll
                for (int nt = 0; nt < 4; ++nt) {
                    acc[mt][nt][reg] += db;
                    E[(size_t)v*Kst + kg*64 + nt*16 + l15] = f2bf(acc[mt][nt][reg]);
                }
            } else {
                #pragma unroll
                for (int nt = 0; nt < 4; ++nt) acc[mt][nt][reg] = -1e30f;
            }
        }
    }
    float mxl[4];
    #pragma unroll
    for (int nt = 0; nt < 4; ++nt) {
        float m = -1e30f;
        #pragma unroll
        for (int mt = 0; mt < 4; ++mt)
            #pragma unroll
            for (int reg = 0; reg < 4; ++reg)
                m = fmaxf(m, acc[mt][nt][reg]);
        m = fmaxf(m, __shfl_xor(m, 16));
        m = fmaxf(m, __shfl_xor(m, 32));
        mxl[nt] = m;
    }
    if (q == 0)
        #pragma unroll
        for (int nt = 0; nt < 4; ++nt) red[wv][nt*16 + l15] = mxl[nt];
    __syncthreads();
    if (tid < 64)
        gmax[tid] = fmaxf(fmaxf(red[0][tid], red[1][tid]), fmaxf(red[2][tid], red[3][tid]));
    __syncthreads();
    #pragma unroll
    for (int nt = 0; nt < 4; ++nt) {
        float g = gmax[nt*16 + l15];
        float s = 0.f;
        #pragma unroll
        for (int mt = 0; mt < 4; ++mt)
            #pragma unroll
            for (int reg = 0; reg < 4; ++reg)
                s += __expf(acc[mt][nt][reg] - g);
        s += __shfl_xor(s, 16);
        s += __shfl_xor(s, 32);
        mxl[nt] = s;
    }
    __syncthreads();
    if (q == 0)
        #pragma unroll
        for (int nt = 0; nt < 4; ++nt) red[wv][nt*16 + l15] = mxl[nt];
    __syncthreads();
    if (tid < 64) {
        int kst = kg*64 + tid;
        float s = red[0][tid] + red[1][tid] + red[2][tid] + red[3][tid];
        part[((size_t)kst*VB2 + vb)*2]     = gmax[tid];
        part[((size_t)kst*VB2 + vb)*2 + 1] = s;
    }
}

// ---------------- K4: combine partials -> lse_em[k] ----------------
__global__ __launch_bounds__(256) void k_em_comb(
    const float* __restrict__ part, float* __restrict__ lse_em)
{
    int k = threadIdx.x;
    float m = -1e30f, s = 0.f;
    for (int vb = 0; vb < VB2; ++vb) {
        float m2 = part[((size_t)k*VB2+vb)*2], s2 = part[((size_t)k*VB2+vb)*2+1];
        if (m2 > m) { s = s*__expf(m - m2) + s2; m = m2; }
        else          s += s2*__expf(m2 - m);
    }
    lse_em[k] = m + logf(s);
}

// ---------------- K5 (MFMA): transition logits Td[r][c] (bf16) + lse_t[r] ----------------
// Phase A is block-parallel: thread (row = tid&63, seg = tid>>6) computes 128 cols of v,
// LN stats via LDS partials; normalize in place. Phase B: 64x256x512 MFMA from LDS.
// Phase C: lse + coalesced Td store staged through the th tile.
__global__ __launch_bounds__(256) void k_trans3(
    const float* __restrict__ tlembs, const float* __restrict__ P0,
    const float* __restrict__ P1, const float* __restrict__ tm_bias,
    const float* __restrict__ tn_g, const float* __restrict__ tn_beta,
    const short* __restrict__ tdw_bf, const float* __restrict__ td_b,
    float* __restrict__ lse_t, unsigned short* __restrict__ Td)
{
    __shared__ short th[64][520];          // 66.5 KB; row stride 1040B -> conflict-free b128
    __shared__ float rstat[64][9];         // padded: stride 9 words spreads banks
    __shared__ float musig[64][2];
    __shared__ float pmax[4][64], psum[4][64], gmax[64];
    int tid = threadIdx.x, lane = tid & 63, wv = tid >> 6;
    int r0 = blockIdx.x * 64;
    int row = tid & 63, seg = tid >> 6;

    // ---- phase A pass 1: v = cat + relu(P0[i0]+P1[i1]+bias), bf16 -> LDS, f32 stats ----
    {
        int r = r0 + row; if (r >= NROWS) r = NROWS - 1;
        int i0 = r / KP1, i1 = r - i0*KP1;
        const float4* p0 = (const float4*)(P0 + (size_t)i0*MD + seg*128);
        const float4* p1 = (const float4*)(P1 + (size_t)i1*MD + seg*128);
        const float4* bj = (const float4*)(tm_bias + seg*128);
        const float4* ct = (seg < 2) ? (const float4*)(tlembs + (size_t)i0*Dd + seg*128)
                                     : (const float4*)(tlembs + (size_t)i1*Dd + (seg-2)*128);
        float s = 0.f, ss = 0.f;
        #pragma unroll 4
        for (int k4 = 0; k4 < 32; k4 += 2) {
            float4 a0 = p0[k4], a1 = p0[k4+1];
            float4 b0 = p1[k4], b1 = p1[k4+1];
            float4 c0 = bj[k4], c1 = bj[k4+1];
            float4 t0 = ct[k4], t1 = ct[k4+1];
            float v0 = t0.x + fmaxf(a0.x+b0.x+c0.x, 0.f);
            float v1 = t0.y + fmaxf(a0.y+b0.y+c0.y, 0.f);
            float v2 = t0.z + fmaxf(a0.z+b0.z+c0.z, 0.f);
            float v3 = t0.w + fmaxf(a0.w+b0.w+c0.w, 0.f);
            float v4 = t1.x + fmaxf(a1.x+b1.x+c1.x, 0.f);
            float v5 = t1.y + fmaxf(a1.y+b1.y+c1.y, 0.f);
            float v6 = t1.z + fmaxf(a1.z+b1.z+c1.z, 0.f);
            float v7 = t1.w + fmaxf(a1.w+b1.w+c1.w, 0.f);
            s  += ((v0+v1)+(v2+v3)) + ((v4+v5)+(v6+v7));
            ss += ((v0*v0+v1*v1)+(v2*v2+v3*v3)) + ((v4*v4+v5*v5)+(v6*v6+v7*v7));
            u32x4 pk;
            pk.x = bfpack(v0, v1);
            pk.y = bfpack(v2, v3);
            pk.z = bfpack(v4, v5);
            pk.w = bfpack(v6, v7);
            *(short8*)&th[row][seg*128 + k4*4] = __builtin_bit_cast(short8, pk);
        }
        rstat[row][seg]     = s;
        rstat[row][4 + seg] = ss;
    }
    __syncthreads();
    if (tid < 64) {
        float s  = (rstat[tid][0] + rstat[tid][1]) + (rstat[tid][2] + rstat[tid][3]);
        float ss = (rstat[tid][4] + rstat[tid][5]) + (rstat[tid][6] + rstat[tid][7]);
        float mu = s * (1.f/MD);
        musig[tid][0] = mu;
        musig[tid][1] = rsqrtf(ss*(1.f/MD) - mu*mu + EPSf);
    }
    __syncthreads();
    // ---- phase A pass 2: normalize in place ----
    {
        float mu = musig[row][0], rs = musig[row][1];
        const float4* g4 = (const float4*)(tn_g + seg*128);
        const float4* e4 = (const float4*)(tn_beta + seg*128);
        #pragma unroll 4
        for (int k4 = 0; k4 < 32; k4 += 2) {
            short8 vv = *(const short8*)&th[row][seg*128 + k4*4];
            float4 g0 = g4[k4], g1 = g4[k4+1];
            float4 e0 = e4[k4], e1 = e4[k4+1];
            float o0 = (bf2f((unsigned short)vv[0]) - mu)*rs*g0.x + e0.x;
            float o1 = (bf2f((unsigned short)vv[1]) - mu)*rs*g0.y + e0.y;
            float o2 = (bf2f((unsigned short)vv[2]) - mu)*rs*g0.z + e0.z;
            float o3 = (bf2f((unsigned short)vv[3]) - mu)*rs*g0.w + e0.w;
            float o4 = (bf2f((unsigned short)vv[4]) - mu)*rs*g1.x + e1.x;
            float o5 = (bf2f((unsigned short)vv[5]) - mu)*rs*g1.y + e1.y;
            float o6 = (bf2f((unsigned short)vv[6]) - mu)*rs*g1.z + e1.z;
            float o7 = (bf2f((unsigned short)vv[7]) - mu)*rs*g1.w + e1.w;
            u32x4 pk;
            pk.x = bfpack(o0, o1);
            pk.y = bfpack(o2, o3);
            pk.z = bfpack(o4, o5);
            pk.w = bfpack(o6, o7);
            *(short8*)&th[row][seg*128 + k4*4] = __builtin_bit_cast(short8, pk);
        }
    }
    __syncthreads();

    // ---- phase B: MFMA (wave wv owns cols [wv*64, wv*64+64)) ----
    int l15 = lane & 15, q = lane >> 4;
    f32x4 acc[4][4];
    #pragma unroll
    for (int rt = 0; rt < 4; ++rt)
        #pragma unroll
        for (int ct = 0; ct < 4; ++ct)
            acc[rt][ct] = (f32x4){0.f, 0.f, 0.f, 0.f};
    const short* tb = tdw_bf + ((size_t)(wv*64 + l15))*MD + q*8;
    #pragma unroll 4
    for (int ks = 0; ks < 16; ++ks) {
        int ko = ks*32 + q*8;
        short8 a0 = *(const short8*)&th[ 0 + l15][ko];
        short8 a1 = *(const short8*)&th[16 + l15][ko];
        short8 a2 = *(const short8*)&th[32 + l15][ko];
        short8 a3 = *(const short8*)&th[48 + l15][ko];
        short8 b0 = *(const short8*)(tb + ks*32);
        short8 b1 = *(const short8*)(tb + 16*MD + ks*32);
        short8 b2 = *(const short8*)(tb + 32*MD + ks*32);
        short8 b3 = *(const short8*)(tb + 48*MD + ks*32);
        acc[0][0] = __builtin_amdgcn_mfma_f32_16x16x32_bf16(a0, b0, acc[0][0], 0,0,0);
        acc[1][0] = __builtin_amdgcn_mfma_f32_16x16x32_bf16(a1, b0, acc[1][0], 0,0,0);
        acc[2][0] = __builtin_amdgcn_mfma_f32_16x16x32_bf16(a2, b0, acc[2][0], 0,0,0);
        acc[3][0] = __builtin_amdgcn_mfma_f32_16x16x32_bf16(a3, b0, acc[3][0], 0,0,0);
        acc[0][1] = __builtin_amdgcn_mfma_f32_16x16x32_bf16(a0, b1, acc[0][1], 0,0,0);
        acc[1][1] = __builtin_amdgcn_mfma_f32_16x16x32_bf16(a1, b1, acc[1][1], 0,0,0);
        acc[2][1] = __builtin_amdgcn_mfma_f32_16x16x32_bf16(a2, b1, acc[2][1], 0,0,0);
        acc[3][1] = __builtin_amdgcn_mfma_f32_16x16x32_bf16(a3, b1, acc[3][1], 0,0,0);
        acc[0][2] = __builtin_amdgcn_mfma_f32_16x16x32_bf16(a0, b2, acc[0][2], 0,0,0);
        acc[1][2] = __builtin_amdgcn_mfma_f32_16x16x32_bf16(a1, b2, acc[1][2], 0,0,0);
        acc[2][2] = __builtin_amdgcn_mfma_f32_16x16x32_bf16(a2, b2, acc[2][2], 0,0,0);
        acc[3][2] = __builtin_amdgcn_mfma_f32_16x16x32_bf16(a3, b2, acc[3][2], 0,0,0);
        acc[0][3] = __builtin_amdgcn_mfma_f32_16x16x32_bf16(a0, b3, acc[0][3], 0,0,0);
        acc[1][3] = __builtin_amdgcn_mfma_f32_16x16x32_bf16(a1, b3, acc[1][3], 0,0,0);
        acc[2][3] = __builtin_amdgcn_mfma_f32_16x16x32_bf16(a2, b3, acc[2][3], 0,0,0);
        acc[3][3] = __builtin_amdgcn_mfma_f32_16x16x32_bf16(a3, b3, acc[3][3], 0,0,0);
    }

    // ---- phase C: bias, stage logits into th (overlay), lse, coalesced Td store ----
    float tbc0 = td_b[wv*64 +  0 + l15];
    float tbc1 = td_b[wv*64 + 16 + l15];
    float tbc2 = td_b[wv*64 + 32 + l15];
    float tbc3 = td_b[wv*64 + 48 + l15];
    #pragma unroll
    for (int rt = 0; rt < 4; ++rt) {
        #pragma unroll
        for (int reg = 0; reg < 4; ++reg) {
            acc[rt][0][reg] += tbc0;
            acc[rt][1][reg] += tbc1;
            acc[rt][2][reg] += tbc2;
            acc[rt][3][reg] += tbc3;
        }
    }
    __syncthreads();   // all waves done reading th fragments
    #pragma unroll
    for (int rt = 0; rt < 4; ++rt) {
        #pragma unroll
        for (int reg = 0; reg < 4; ++reg) {
            int rl = rt*16 + q*4 + reg;
            th[rl][wv*64 +  0 + l15] = (short)f2bf(acc[rt][0][reg]);
            th[rl][wv*64 + 16 + l15] = (short)f2bf(acc[rt][1][reg]);
            th[rl][wv*64 + 32 + l15] = (short)f2bf(acc[rt][2][reg]);
            th[rl][wv*64 + 48 + l15] = (short)f2bf(acc[rt][3][reg]);
        }
    }
    #pragma unroll
    for (int rt = 0; rt < 4; ++rt) {
        #pragma unroll
        for (int reg = 0; reg < 4; ++reg) {
            float m = fmaxf(fmaxf(acc[rt][0][reg], acc[rt][1][reg]),
                            fmaxf(acc[rt][2][reg], acc[rt][3][reg]));
            m = fmaxf(m, __shfl_xor(m, 1));
            m = fmaxf(m, __shfl_xor(m, 2));
            m = fmaxf(m, __shfl_xor(m, 4));
            m = fmaxf(m, __shfl_xor(m, 8));
            if (l15 == 0) pmax[wv][rt*16 + q*4 + reg] = m;
        }
    }
    __syncthreads();
    if (tid < 64)
        gmax[tid] = fmaxf(fmaxf(pmax[0][tid], pmax[1][tid]),
                          fmaxf(pmax[2][tid], pmax[3][tid]));
    __syncthreads();
    #pragma unroll
    for (int rt = 0; rt < 4; ++rt) {
        #pragma unroll
        for (int reg = 0; reg < 4; ++reg) {
            int rw = rt*16 + q*4 + reg;
            float g = gmax[rw];
            float s = __expf(acc[rt][0][reg] - g) + __expf(acc[rt][1][reg] - g)
                    + __expf(acc[rt][2][reg] - g) + __expf(acc[rt][3][reg] - g);
            s += __shfl_xor(s, 1);
            s += __shfl_xor(s, 2);
            s += __shfl_xor(s, 4);
            s += __shfl_xor(s, 8);
            if (l15 == 0) psum[wv][rw] = s;
        }
    }
    __syncthreads();
    if (tid < 64) {
        int r = r0 + tid;
        if (r < NROWS)
            lse_t[r] = gmax[tid] + logf(psum[0][tid] + psum[1][tid] + psum[2][tid] + psum[3][tid]);
    }
    // contiguous 32 KB Td block store: thread -> 128 B
    {
        int srow = tid >> 2, scol = (tid & 3) * 64;
        long gr = (long)r0 + srow;
        if (gr < NROWS) {
            unsigned short* dst = Td + (size_t)gr*Kst + scol;
            #pragma unroll
            for (int k = 0; k < 8; ++k)
                *(short8*)(dst + k*8) = *(const short8*)&th[srow][scol + k*8];
        }
    }
}

// ---------------- K6: gather = 2 table lookups per (t,b) ----------------
#define TCH 4
__global__ __launch_bounds__(256) void k_gather2(
    const int* __restrict__ x, const int* __restrict__ z,
    const unsigned short* __restrict__ E, const float* __restrict__ lse_em,
    const unsigned short* __restrict__ Td, const float* __restrict__ lse_t,
    float* __restrict__ out)
{
    int b = threadIdx.x;
    int t0 = blockIdx.x * TCH;
    float s = 0.f;
    #pragma unroll
    for (int i = 0; i < TCH; ++i) {
        int t = t0 + i;
        int zc = z[t*Bb + b];
        int xv = x[t*Bb + b];
        int i0 = (t >= 2) ? z[(t-2)*Bb + b] : Kst;
        int i1 = (t >= 1) ? z[(t-1)*Bb + b] : Kst;
        int lin = i0*KP1 + i1;
        float em = bf2f(E[(size_t)xv*Kst + zc])  - lse_em[zc];
        float tr = bf2f(Td[(size_t)lin*Kst + zc]) - lse_t[lin];
        s += em + tr;
    }
    atomicAdd(&out[b], s);
}

extern "C" void kernel_launch(void* const* d_in, const int* in_sizes, int n_in,
                              void* d_out, int out_size, void* d_ws, size_t ws_size,
                              hipStream_t stream)
{
    const int*   x       = (const int*)  d_in[0];
    const int*   z       = (const int*)  d_in[1];
    const float* lembs   = (const float*)d_in[2];
    const float* tlembs  = (const float*)d_in[3];
    const float* dec_W   = (const float*)d_in[4];
    const float* dec_b   = (const float*)d_in[5];
    const float* em_W    = (const float*)d_in[6];
    const float* em_bias = (const float*)d_in[7];
    const float* em_g    = (const float*)d_in[8];
    const float* em_beta = (const float*)d_in[9];
    const float* td_W    = (const float*)d_in[10];
    const float* td_b    = (const float*)d_in[11];
    const float* tm_W    = (const float*)d_in[12];
    const float* tm_bias = (const float*)d_in[13];
    const float* tn_g    = (const float*)d_in[14];
    const float* tn_beta = (const float*)d_in[15];
    float* out = (float*)d_out;

    float* ws     = (float*)d_ws;
    float* P0     = ws;                    // 131584
    float* P1     = P0 + 131584;           // 131584
    float* lse_em = P1 + 131584;           // 256
    float* part   = lse_em + 256;          // 256*196*2 = 100352
    float* lse_t  = part + 100352;         // 66049 (+pad)
    unsigned short* tdw_bf = (unsigned short*)(lse_t + 66052);  // 131072 ushort
    unsigned short* h_bf   = tdw_bf + 131072;                   // 65536 ushort
    unsigned short* E      = h_bf + 65536;                      // 50176*256 ushort (25.7MB)
    unsigned short* Td     = E + (size_t)50176*256;             // 66049*256 ushort (33.8MB)
    // total ~61.6 MB of workspace

    hipMemsetAsync(out, 0, Bb*sizeof(float), stream);
    k_h<<<Kst, 256, 0, stream>>>(lembs, em_W, em_bias, em_g, em_beta, h_bf);
    k_P<<<KP1, 256, 0, stream>>>(tlembs, tm_W, P0, P1);
    k_tdw<<<128, 256, 0, stream>>>(td_W, tdw_bf);
    k_em_mfma<<<dim3(VB2, 4), 256, 0, stream>>>(dec_W, dec_b, h_bf, part, E);
    k_em_comb<<<1, Kst, 0, stream>>>(part, lse_em);
    k_trans3<<<(NROWS + 63)/64, 256, 0, stream>>>(tlembs, P0, P1, tm_bias,
                                                  tn_g, tn_beta, (const short*)tdw_bf,
                                                  td_b, lse_t, Td);
    k_gather2<<<Tt/TCH, 256, 0, stream>>>(x, z, E, lse_em, Td, lse_t, out);
}

// Round 6
// 412.845 us; speedup vs baseline: 1.1159x; 1.1159x over previous
//
#include <hip/hip_runtime.h>

#define Kst 256
#define Dd 256
#define Vv 50000
#define Tt 512
#define Bb 256
#define KP1 257
#define MD 512
#define NROWS (KP1*KP1)   // 66049
#define EPSf 1e-5f

#define VB2 196           // ceil(50000/256) vocab blocks for MFMA emission kernel

typedef __attribute__((ext_vector_type(8))) short short8;
typedef __attribute__((ext_vector_type(4))) short short4v;
typedef __attribute__((ext_vector_type(4))) float f32x4;
typedef __attribute__((ext_vector_type(4))) unsigned u32x4;
typedef __attribute__((ext_vector_type(2))) unsigned u32x2;

__device__ __forceinline__ unsigned short f2bf(float f) {
    unsigned u = __builtin_bit_cast(unsigned, f);
    unsigned r = (u + 0x7fffu + ((u >> 16) & 1u)) >> 16;
    return (unsigned short)r;
}
__device__ __forceinline__ float bf2f(unsigned short u) {
    return __builtin_bit_cast(float, ((unsigned)u) << 16);
}
__device__ __forceinline__ unsigned bfpack(float lo, float hi) {
    return __builtin_amdgcn_perm(__builtin_bit_cast(unsigned, hi),
                                 __builtin_bit_cast(unsigned, lo), 0x07060302u);
}

// ---------------- K1: emission hidden h = LN(lembs + relu(lembs@em_W.T + b)) -> bf16 ----------------
__global__ __launch_bounds__(256) void k_h(
    const float* __restrict__ lembs, const float* __restrict__ em_W,
    const float* __restrict__ em_bias, const float* __restrict__ em_g,
    const float* __restrict__ em_beta, unsigned short* __restrict__ h_bf)
{
    int k = blockIdx.x, d = threadIdx.x;
    __shared__ float lrow[Dd];
    __shared__ float red[256];
    lrow[d] = lembs[k*Dd + d];
    __syncthreads();
    float acc = em_bias[d];
    const float4* w4 = (const float4*)(em_W + (size_t)d*Dd);
    for (int j4 = 0; j4 < Dd/4; ++j4) {
        float4 w = w4[j4];
        acc += w.x*lrow[4*j4] + w.y*lrow[4*j4+1] + w.z*lrow[4*j4+2] + w.w*lrow[4*j4+3];
    }
    float val = lrow[d] + fmaxf(acc, 0.f);
    red[d] = val; __syncthreads();
    for (int s = 128; s > 0; s >>= 1) { if (d < s) red[d] += red[d+s]; __syncthreads(); }
    float mu = red[0] * (1.f/Dd);
    __syncthreads();
    float c = val - mu;
    red[d] = c*c; __syncthreads();
    for (int s = 128; s > 0; s >>= 1) { if (d < s) red[d] += red[d+s]; __syncthreads(); }
    float rstd = rsqrtf(red[0] * (1.f/Dd) + EPSf);
    float o = c * rstd * em_g[d] + em_beta[d];
    h_bf[k*Dd + d] = f2bf(o);
}

// ---------------- K2: P0[i,j] = tlembs[i]@tm_W[j,0:256], P1[i,j] = tlembs[i]@tm_W[j,256:512] ----------------
__global__ __launch_bounds__(256) void k_P(
    const float* __restrict__ tlembs, const float* __restrict__ tm_W,
    float* __restrict__ P0, float* __restrict__ P1)
{
    int i = blockIdx.x;            // 0..256
    int tid = threadIdx.x;
    __shared__ float tl[Dd];
    tl[tid] = tlembs[i*Dd + tid];
    __syncthreads();
    for (int half = 0; half < 2; ++half) {
        int j = tid + half*256;
        float a0 = 0.f, a1 = 0.f;
        const float4* w4 = (const float4*)(tm_W + (size_t)j*MD);
        for (int l4 = 0; l4 < 64; ++l4) {
            float4 w = w4[l4];
            a0 += w.x*tl[4*l4] + w.y*tl[4*l4+1] + w.z*tl[4*l4+2] + w.w*tl[4*l4+3];
        }
        for (int l4 = 64; l4 < 128; ++l4) {
            float4 w = w4[l4];
            int l = 4*l4 - 256;
            a1 += w.x*tl[l] + w.y*tl[l+1] + w.z*tl[l+2] + w.w*tl[l+3];
        }
        P0[(size_t)i*MD + j] = a0;
        P1[(size_t)i*MD + j] = a1;
    }
}

// ---------------- K2b: td_W -> bf16 copy ----------------
__global__ __launch_bounds__(256) void k_tdw(
    const float* __restrict__ td_W, unsigned short* __restrict__ tdw_bf)
{
    int i = blockIdx.x*256 + threadIdx.x;
    float4 v = ((const float4*)td_W)[i];
    short4v o;
    o.x = (short)f2bf(v.x); o.y = (short)f2bf(v.y);
    o.z = (short)f2bf(v.z); o.w = (short)f2bf(v.w);
    *(short4v*)(tdw_bf + (size_t)i*4) = o;
}

// ---------------- K3 (MFMA): emission logits E[v][k] (bf16) + logsumexp partials ----------------
__global__ __launch_bounds__(256) void k_em_mfma(
    const float* __restrict__ dec_W, const float* __restrict__ dec_b,
    const unsigned short* __restrict__ h_bf, float* __restrict__ part,
    unsigned short* __restrict__ E)
{
    int vb = blockIdx.x, kg = blockIdx.y;
    int tid = threadIdx.x, lane = tid & 63, wv = tid >> 6;
    int l15 = lane & 15, q = lane >> 4;
    __shared__ short hs[64][264];      // stride 264: 2-way bank aliasing (free)
    __shared__ float red[4][64];
    __shared__ float gmax[64];

    {
        int row = tid >> 2, c0 = (tid & 3) * 64;
        const short8* src = (const short8*)(h_bf + (size_t)(kg*64 + row)*Dd + c0);
        #pragma unroll
        for (int u = 0; u < 8; ++u)
            *(short8*)&hs[row][c0 + u*8] = src[u];
    }
    __syncthreads();

    const float* aptr[4];
    #pragma unroll
    for (int mt = 0; mt < 4; ++mt) {
        int v = vb*256 + wv*64 + mt*16 + l15;
        if (v > Vv-1) v = Vv-1;
        aptr[mt] = dec_W + (size_t)v*Dd + q*8;
    }
    f32x4 acc[4][4];
    #pragma unroll
    for (int mt = 0; mt < 4; ++mt)
        #pragma unroll
        for (int nt = 0; nt < 4; ++nt)
            acc[mt][nt] = (f32x4){0.f,0.f,0.f,0.f};

    for (int ks = 0; ks < 8; ++ks) {
        short8 a[4];
        #pragma unroll
        for (int mt = 0; mt < 4; ++mt) {
            float4 f0 = *(const float4*)(aptr[mt] + ks*32);
            float4 f1 = *(const float4*)(aptr[mt] + ks*32 + 4);
            u32x4 pk;
            pk.x = bfpack(f0.x, f0.y);
            pk.y = bfpack(f0.z, f0.w);
            pk.z = bfpack(f1.x, f1.y);
            pk.w = bfpack(f1.z, f1.w);
            a[mt] = __builtin_bit_cast(short8, pk);
        }
        short8 b0 = *(const short8*)&hs[ 0 + l15][ks*32 + q*8];
        short8 b1 = *(const short8*)&hs[16 + l15][ks*32 + q*8];
        short8 b2 = *(const short8*)&hs[32 + l15][ks*32 + q*8];
        short8 b3 = *(const short8*)&hs[48 + l15][ks*32 + q*8];
        #pragma unroll
        for (int mt = 0; mt < 4; ++mt) {
            acc[mt][0] = __builtin_amdgcn_mfma_f32_16x16x32_bf16(a[mt], b0, acc[mt][0], 0,0,0);
            acc[mt][1] = __builtin_amdgcn_mfma_f32_16x16x32_bf16(a[mt], b1, acc[mt][1], 0,0,0);
            acc[mt][2] = __builtin_amdgcn_mfma_f32_16x16x32_bf16(a[mt], b2, acc[mt][2], 0,0,0);
            acc[mt][3] = __builtin_amdgcn_mfma_f32_16x16x32_bf16(a[mt], b3, acc[mt][3], 0,0,0);
        }
    }

    // add dec_b, store bf16 logits, mask OOB rows (C layout: row=q*4+reg, col=nt*16+l15)
    #pragma unroll
    for (int mt = 0; mt < 4; ++mt) {
        int vbase = vb*256 + wv*64 + mt*16 + q*4;
        #pragma unroll
        for (int reg = 0; reg < 4; ++reg) {
            int v = vbase + reg;
            if (v < Vv) {
                float db = dec_b[v];
                #pragma unroll
                for (int nt = 0; nt < 4; ++nt) {
                    acc[mt][nt][reg] += db;
                    E[(size_t)v*Kst + kg*64 + nt*16 + l15] = f2bf(acc[mt][nt][reg]);
                }
            } else {
                #pragma unroll
                for (int nt = 0; nt < 4; ++nt) acc[mt][nt][reg] = -1e30f;
            }
        }
    }
    float mxl[4];
    #pragma unroll
    for (int nt = 0; nt < 4; ++nt) {
        float m = -1e30f;
        #pragma unroll
        for (int mt = 0; mt < 4; ++mt)
            #pragma unroll
            for (int reg = 0; reg < 4; ++reg)
                m = fmaxf(m, acc[mt][nt][reg]);
        m = fmaxf(m, __shfl_xor(m, 16));
        m = fmaxf(m, __shfl_xor(m, 32));
        mxl[nt] = m;
    }
    if (q == 0)
        #pragma unroll
        for (int nt = 0; nt < 4; ++nt) red[wv][nt*16 + l15] = mxl[nt];
    __syncthreads();
    if (tid < 64)
        gmax[tid] = fmaxf(fmaxf(red[0][tid], red[1][tid]), fmaxf(red[2][tid], red[3][tid]));
    __syncthreads();
    #pragma unroll
    for (int nt = 0; nt < 4; ++nt) {
        float g = gmax[nt*16 + l15];
        float s = 0.f;
        #pragma unroll
        for (int mt = 0; mt < 4; ++mt)
            #pragma unroll
            for (int reg = 0; reg < 4; ++reg)
                s += __expf(acc[mt][nt][reg] - g);
        s += __shfl_xor(s, 16);
        s += __shfl_xor(s, 32);
        mxl[nt] = s;
    }
    __syncthreads();
    if (q == 0)
        #pragma unroll
        for (int nt = 0; nt < 4; ++nt) red[wv][nt*16 + l15] = mxl[nt];
    __syncthreads();
    if (tid < 64) {
        int kst = kg*64 + tid;
        float s = red[0][tid] + red[1][tid] + red[2][tid] + red[3][tid];
        part[((size_t)kst*VB2 + vb)*2]     = gmax[tid];
        part[((size_t)kst*VB2 + vb)*2 + 1] = s;
    }
}

// ---------------- K4: combine partials -> lse_em[k] ----------------
__global__ __launch_bounds__(256) void k_em_comb(
    const float* __restrict__ part, float* __restrict__ lse_em)
{
    int k = threadIdx.x;
    float m = -1e30f, s = 0.f;
    for (int vb = 0; vb < VB2; ++vb) {
        float m2 = part[((size_t)k*VB2+vb)*2], s2 = part[((size_t)k*VB2+vb)*2+1];
        if (m2 > m) { s = s*__expf(m - m2) + s2; m = m2; }
        else          s += s2*__expf(m2 - m);
    }
    lse_em[k] = m + logf(s);
}

// ---------------- K5 (MFMA): transition logits Td[r][c] (bf16) + lse_t[r] ----------------
// Phase A pass 1: wave-per-row COALESCED staging (lane = column), NO in-loop reductions
//   -> 32 independent load/compute/LDS-store iterations, fully pipelineable.
// Pass 2: LN stats from LDS (thread-per-(row,seg) partials). Pass 3: normalize in place.
// Phase B: 64x256x512 MFMA. Phase C: lse + coalesced Td store via LDS overlay.
__global__ __launch_bounds__(256) void k_trans4(
    const float* __restrict__ tlembs, const float* __restrict__ P0,
    const float* __restrict__ P1, const float* __restrict__ tm_bias,
    const float* __restrict__ tn_g, const float* __restrict__ tn_beta,
    const short* __restrict__ tdw_bf, const float* __restrict__ td_b,
    float* __restrict__ lse_t, unsigned short* __restrict__ Td)
{
    __shared__ short th[64][520];          // 66.5 KB; row stride 1040B
    __shared__ float rstat[64][9];
    __shared__ float musig[64][2];
    __shared__ float pmax[4][64], psum[4][64], gmax[64];
    int tid = threadIdx.x, lane = tid & 63, wv = tid >> 6;
    int r0 = blockIdx.x * 64;

    // ---- phase A pass 1: coalesced, dependency-free staging ----
    {
        const float4* bias0 = (const float4*)tm_bias;
        const float4* bias1 = (const float4*)(tm_bias + 256);
        for (int i = 0; i < 16; ++i) {
            int row = wv*16 + i;
            int r = r0 + row; if (r >= NROWS) r = NROWS - 1;
            int i0 = r / KP1, i1 = r - i0*KP1;
            float4 a0 = ((const float4*)(P0 + (size_t)i0*MD))[lane];
            float4 b0 = ((const float4*)(P1 + (size_t)i1*MD))[lane];
            float4 t0 = ((const float4*)(tlembs + (size_t)i0*Dd))[lane];
            float4 c0 = bias0[lane];
            float4 a1 = ((const float4*)(P0 + (size_t)i0*MD + 256))[lane];
            float4 b1 = ((const float4*)(P1 + (size_t)i1*MD + 256))[lane];
            float4 t1 = ((const float4*)(tlembs + (size_t)i1*Dd))[lane];
            float4 c1 = bias1[lane];
            float v0 = t0.x + fmaxf(a0.x+b0.x+c0.x, 0.f);
            float v1 = t0.y + fmaxf(a0.y+b0.y+c0.y, 0.f);
            float v2 = t0.z + fmaxf(a0.z+b0.z+c0.z, 0.f);
            float v3 = t0.w + fmaxf(a0.w+b0.w+c0.w, 0.f);
            float v4 = t1.x + fmaxf(a1.x+b1.x+c1.x, 0.f);
            float v5 = t1.y + fmaxf(a1.y+b1.y+c1.y, 0.f);
            float v6 = t1.z + fmaxf(a1.z+b1.z+c1.z, 0.f);
            float v7 = t1.w + fmaxf(a1.w+b1.w+c1.w, 0.f);
            u32x2 p0; p0.x = bfpack(v0, v1); p0.y = bfpack(v2, v3);
            u32x2 p1; p1.x = bfpack(v4, v5); p1.y = bfpack(v6, v7);
            *(u32x2*)&th[row][lane*4]       = p0;
            *(u32x2*)&th[row][256 + lane*4] = p1;
        }
    }
    __syncthreads();
    // ---- pass 2: LN stats from LDS ----
    {
        int row = tid & 63, seg = tid >> 6;
        float s = 0.f, ss = 0.f;
        #pragma unroll
        for (int k8 = 0; k8 < 16; ++k8) {
            short8 vv = *(const short8*)&th[row][seg*128 + k8*8];
            #pragma unroll
            for (int e = 0; e < 8; ++e) {
                float f = bf2f((unsigned short)vv[e]);
                s += f; ss += f*f;
            }
        }
        rstat[row][seg]     = s;
        rstat[row][4 + seg] = ss;
    }
    __syncthreads();
    if (tid < 64) {
        float s  = (rstat[tid][0] + rstat[tid][1]) + (rstat[tid][2] + rstat[tid][3]);
        float ss = (rstat[tid][4] + rstat[tid][5]) + (rstat[tid][6] + rstat[tid][7]);
        float mu = s * (1.f/MD);
        musig[tid][0] = mu;
        musig[tid][1] = rsqrtf(ss*(1.f/MD) - mu*mu + EPSf);
    }
    __syncthreads();
    // ---- pass 3: normalize in place ----
    {
        int row = tid & 63, seg = tid >> 6;
        float mu = musig[row][0], rs = musig[row][1];
        const float4* g4 = (const float4*)(tn_g + seg*128);
        const float4* e4 = (const float4*)(tn_beta + seg*128);
        #pragma unroll 4
        for (int k4 = 0; k4 < 32; k4 += 2) {
            short8 vv = *(const short8*)&th[row][seg*128 + k4*4];
            float4 g0 = g4[k4], g1 = g4[k4+1];
            float4 e0 = e4[k4], e1 = e4[k4+1];
            float o0 = (bf2f((unsigned short)vv[0]) - mu)*rs*g0.x + e0.x;
            float o1 = (bf2f((unsigned short)vv[1]) - mu)*rs*g0.y + e0.y;
            float o2 = (bf2f((unsigned short)vv[2]) - mu)*rs*g0.z + e0.z;
            float o3 = (bf2f((unsigned short)vv[3]) - mu)*rs*g0.w + e0.w;
            float o4 = (bf2f((unsigned short)vv[4]) - mu)*rs*g1.x + e1.x;
            float o5 = (bf2f((unsigned short)vv[5]) - mu)*rs*g1.y + e1.y;
            float o6 = (bf2f((unsigned short)vv[6]) - mu)*rs*g1.z + e1.z;
            float o7 = (bf2f((unsigned short)vv[7]) - mu)*rs*g1.w + e1.w;
            u32x4 pk;
            pk.x = bfpack(o0, o1);
            pk.y = bfpack(o2, o3);
            pk.z = bfpack(o4, o5);
            pk.w = bfpack(o6, o7);
            *(short8*)&th[row][seg*128 + k4*4] = __builtin_bit_cast(short8, pk);
        }
    }
    __syncthreads();

    // ---- phase B: MFMA (wave wv owns cols [wv*64, wv*64+64)) ----
    int l15 = lane & 15, q = lane >> 4;
    f32x4 acc[4][4];
    #pragma unroll
    for (int rt = 0; rt < 4; ++rt)
        #pragma unroll
        for (int ct = 0; ct < 4; ++ct)
            acc[rt][ct] = (f32x4){0.f, 0.f, 0.f, 0.f};
    const short* tb = tdw_bf + ((size_t)(wv*64 + l15))*MD + q*8;
    #pragma unroll 4
    for (int ks = 0; ks < 16; ++ks) {
        int ko = ks*32 + q*8;
        short8 a0 = *(const short8*)&th[ 0 + l15][ko];
        short8 a1 = *(const short8*)&th[16 + l15][ko];
        short8 a2 = *(const short8*)&th[32 + l15][ko];
        short8 a3 = *(const short8*)&th[48 + l15][ko];
        short8 b0 = *(const short8*)(tb + ks*32);
        short8 b1 = *(const short8*)(tb + 16*MD + ks*32);
        short8 b2 = *(const short8*)(tb + 32*MD + ks*32);
        short8 b3 = *(const short8*)(tb + 48*MD + ks*32);
        acc[0][0] = __builtin_amdgcn_mfma_f32_16x16x32_bf16(a0, b0, acc[0][0], 0,0,0);
        acc[1][0] = __builtin_amdgcn_mfma_f32_16x16x32_bf16(a1, b0, acc[1][0], 0,0,0);
        acc[2][0] = __builtin_amdgcn_mfma_f32_16x16x32_bf16(a2, b0, acc[2][0], 0,0,0);
        acc[3][0] = __builtin_amdgcn_mfma_f32_16x16x32_bf16(a3, b0, acc[3][0], 0,0,0);
        acc[0][1] = __builtin_amdgcn_mfma_f32_16x16x32_bf16(a0, b1, acc[0][1], 0,0,0);
        acc[1][1] = __builtin_amdgcn_mfma_f32_16x16x32_bf16(a1, b1, acc[1][1], 0,0,0);
        acc[2][1] = __builtin_amdgcn_mfma_f32_16x16x32_bf16(a2, b1, acc[2][1], 0,0,0);
        acc[3][1] = __builtin_amdgcn_mfma_f32_16x16x32_bf16(a3, b1, acc[3][1], 0,0,0);
        acc[0][2] = __builtin_amdgcn_mfma_f32_16x16x32_bf16(a0, b2, acc[0][2], 0,0,0);
        acc[1][2] = __builtin_amdgcn_mfma_f32_16x16x32_bf16(a1, b2, acc[1][2], 0,0,0);
        acc[2][2] = __builtin_amdgcn_mfma_f32_16x16x32_bf16(a2, b2, acc[2][2], 0,0,0);
        acc[3][2] = __builtin_amdgcn_mfma_f32_16x16x32_bf16(a3, b2, acc[3][2], 0,0,0);
        acc[0][3] = __builtin_amdgcn_mfma_f32_16x16x32_bf16(a0, b3, acc[0][3], 0,0,0);
        acc[1][3] = __builtin_amdgcn_mfma_f32_16x16x32_bf16(a1, b3, acc[1][3], 0,0,0);
        acc[2][3] = __builtin_amdgcn_mfma_f32_16x16x32_bf16(a2, b3, acc[2][3], 0,0,0);
        acc[3][3] = __builtin_amdgcn_mfma_f32_16x16x32_bf16(a3, b3, acc[3][3], 0,0,0);
    }

    // ---- phase C: bias, stage logits into th (overlay), lse, coalesced Td store ----
    float tbc0 = td_b[wv*64 +  0 + l15];
    float tbc1 = td_b[wv*64 + 16 + l15];
    float tbc2 = td_b[wv*64 + 32 + l15];
    float tbc3 = td_b[wv*64 + 48 + l15];
    #pragma unroll
    for (int rt = 0; rt < 4; ++rt) {
        #pragma unroll
        for (int reg = 0; reg < 4; ++reg) {
            acc[rt][0][reg] += tbc0;
            acc[rt][1][reg] += tbc1;
            acc[rt][2][reg] += tbc2;
            acc[rt][3][reg] += tbc3;
        }
    }
    __syncthreads();   // all waves done reading th fragments
    #pragma unroll
    for (int rt = 0; rt < 4; ++rt) {
        #pragma unroll
        for (int reg = 0; reg < 4; ++reg) {
            int rl = rt*16 + q*4 + reg;
            th[rl][wv*64 +  0 + l15] = (short)f2bf(acc[rt][0][reg]);
            th[rl][wv*64 + 16 + l15] = (short)f2bf(acc[rt][1][reg]);
            th[rl][wv*64 + 32 + l15] = (short)f2bf(acc[rt][2][reg]);
            th[rl][wv*64 + 48 + l15] = (short)f2bf(acc[rt][3][reg]);
        }
    }
    #pragma unroll
    for (int rt = 0; rt < 4; ++rt) {
        #pragma unroll
        for (int reg = 0; reg < 4; ++reg) {
            float m = fmaxf(fmaxf(acc[rt][0][reg], acc[rt][1][reg]),
                            fmaxf(acc[rt][2][reg], acc[rt][3][reg]));
            m = fmaxf(m, __shfl_xor(m, 1));
            m = fmaxf(m, __shfl_xor(m, 2));
            m = fmaxf(m, __shfl_xor(m, 4));
            m = fmaxf(m, __shfl_xor(m, 8));
            if (l15 == 0) pmax[wv][rt*16 + q*4 + reg] = m;
        }
    }
    __syncthreads();
    if (tid < 64)
        gmax[tid] = fmaxf(fmaxf(pmax[0][tid], pmax[1][tid]),
                          fmaxf(pmax[2][tid], pmax[3][tid]));
    __syncthreads();
    #pragma unroll
    for (int rt = 0; rt < 4; ++rt) {
        #pragma unroll
        for (int reg = 0; reg < 4; ++reg) {
            int rw = rt*16 + q*4 + reg;
            float g = gmax[rw];
            float s = __expf(acc[rt][0][reg] - g) + __expf(acc[rt][1][reg] - g)
                    + __expf(acc[rt][2][reg] - g) + __expf(acc[rt][3][reg] - g);
            s += __shfl_xor(s, 1);
            s += __shfl_xor(s, 2);
            s += __shfl_xor(s, 4);
            s += __shfl_xor(s, 8);
            if (l15 == 0) psum[wv][rw] = s;
        }
    }
    __syncthreads();
    if (tid < 64) {
        int r = r0 + tid;
        if (r < NROWS)
            lse_t[r] = gmax[tid] + logf(psum[0][tid] + psum[1][tid] + psum[2][tid] + psum[3][tid]);
    }
    // contiguous 32 KB Td block store: thread -> 128 B
    {
        int srow = tid >> 2, scol = (tid & 3) * 64;
        long gr = (long)r0 + srow;
        if (gr < NROWS) {
            unsigned short* dst = Td + (size_t)gr*Kst + scol;
            #pragma unroll
            for (int k = 0; k < 8; ++k)
                *(short8*)(dst + k*8) = *(const short8*)&th[srow][scol + k*8];
        }
    }
}

// ---------------- K6: gather = 2 table lookups per (t,b) ----------------
#define TCH 4
__global__ __launch_bounds__(256) void k_gather2(
    const int* __restrict__ x, const int* __restrict__ z,
    const unsigned short* __restrict__ E, const float* __restrict__ lse_em,
    const unsigned short* __restrict__ Td, const float* __restrict__ lse_t,
    float* __restrict__ out)
{
    int b = threadIdx.x;
    int t0 = blockIdx.x * TCH;
    float s = 0.f;
    #pragma unroll
    for (int i = 0; i < TCH; ++i) {
        int t = t0 + i;
        int zc = z[t*Bb + b];
        int xv = x[t*Bb + b];
        int i0 = (t >= 2) ? z[(t-2)*Bb + b] : Kst;
        int i1 = (t >= 1) ? z[(t-1)*Bb + b] : Kst;
        int lin = i0*KP1 + i1;
        float em = bf2f(E[(size_t)xv*Kst + zc])  - lse_em[zc];
        float tr = bf2f(Td[(size_t)lin*Kst + zc]) - lse_t[lin];
        s += em + tr;
    }
    atomicAdd(&out[b], s);
}

extern "C" void kernel_launch(void* const* d_in, const int* in_sizes, int n_in,
                              void* d_out, int out_size, void* d_ws, size_t ws_size,
                              hipStream_t stream)
{
    const int*   x       = (const int*)  d_in[0];
    const int*   z       = (const int*)  d_in[1];
    const float* lembs   = (const float*)d_in[2];
    const float* tlembs  = (const float*)d_in[3];
    const float* dec_W   = (const float*)d_in[4];
    const float* dec_b   = (const float*)d_in[5];
    const float* em_W    = (const float*)d_in[6];
    const float* em_bias = (const float*)d_in[7];
    const float* em_g    = (const float*)d_in[8];
    const float* em_beta = (const float*)d_in[9];
    const float* td_W    = (const float*)d_in[10];
    const float* td_b    = (const float*)d_in[11];
    const float* tm_W    = (const float*)d_in[12];
    const float* tm_bias = (const float*)d_in[13];
    const float* tn_g    = (const float*)d_in[14];
    const float* tn_beta = (const float*)d_in[15];
    float* out = (float*)d_out;

    float* ws     = (float*)d_ws;
    float* P0     = ws;                    // 131584
    float* P1     = P0 + 131584;           // 131584
    float* lse_em = P1 + 131584;           // 256
    float* part   = lse_em + 256;          // 256*196*2 = 100352
    float* lse_t  = part + 100352;         // 66049 (+pad)
    unsigned short* tdw_bf = (unsigned short*)(lse_t + 66052);  // 131072 ushort
    unsigned short* h_bf   = tdw_bf + 131072;                   // 65536 ushort
    unsigned short* E      = h_bf + 65536;                      // 50176*256 ushort (25.7MB)
    unsigned short* Td     = E + (size_t)50176*256;             // 66049*256 ushort (33.8MB)
    // total ~61.6 MB of workspace

    hipMemsetAsync(out, 0, Bb*sizeof(float), stream);
    k_h<<<Kst, 256, 0, stream>>>(lembs, em_W, em_bias, em_g, em_beta, h_bf);
    k_P<<<KP1, 256, 0, stream>>>(tlembs, tm_W, P0, P1);
    k_tdw<<<128, 256, 0, stream>>>(td_W, tdw_bf);
    k_em_mfma<<<dim3(VB2, 4), 256, 0, stream>>>(dec_W, dec_b, h_bf, part, E);
    k_em_comb<<<1, Kst, 0, stream>>>(part, lse_em);
    k_trans4<<<(NROWS + 63)/64, 256, 0, stream>>>(tlembs, P0, P1, tm_bias,
                                                  tn_g, tn_beta, (const short*)tdw_bf,
                                                  td_b, lse_t, Td);
    k_gather2<<<Tt/TCH, 256, 0, stream>>>(x, z, E, lse_em, Td, lse_t, out);
}